// Round 5
// baseline (1828.950 us; speedup 1.0000x reference)
//
#include <hip/hip_runtime.h>
#include <hip/hip_bf16.h>

// GroupedExperts: out[t] = (silu(x@w1[e]^T) * (x@w3[e]^T)) @ w2[e]^T
// E=8, T=16384, D=2048, H=5632; tokens pre-sorted by expert, even split.
//
// Round 5: ring-4 deep pipeline. 256x256 tile, BK=32, 8 waves (2Mx4N),
// 4 LDS slots x 32KiB (stage tile t+3 while computing tile t), ONE
// vmcnt(8) + ONE barrier per K-tile (3-tile stage->read distance >> HBM
// latency). 16x16x32 MFMA (verified conflict-free read pattern), swizzle
// s' = q ^ ((row>>1)&3) on 64B rows; staging source pre-applies inverse
// (per-lane constant (l&3)^((l>>3)&3)); linear global_load_lds dest.
// gate/up fused via 16-row w13 interleave (unchanged from R3).

typedef __bf16 bf16x8 __attribute__((ext_vector_type(8)));
typedef float f32x4 __attribute__((ext_vector_type(4)));
typedef unsigned short u16x8 __attribute__((ext_vector_type(8)));

constexpr int E = 8;
constexpr int T = 16384;
constexpr int D = 2048;
constexpr int H = 5632;

#define DEV static __device__ __forceinline__

DEV unsigned short f2bf(float f) {
    unsigned u = __builtin_bit_cast(unsigned, f);
    u = (u + 0x7FFFu + ((u >> 16) & 1u)) >> 16;   // RNE
    return (unsigned short)u;
}

DEV void gload16(const void* g, void* l) {
    __builtin_amdgcn_global_load_lds(
        (const __attribute__((address_space(1))) void*)g,
        (__attribute__((address_space(3))) void*)l, 16, 0, 0);
}

DEV f32x4 mfma16(bf16x8 a, bf16x8 b, f32x4 c) {
    return __builtin_amdgcn_mfma_f32_16x16x32_bf16(a, b, c, 0, 0, 0);
}

DEV void cvt8(const float* src, unsigned short* dst) {
    float4 a = *(const float4*)src;
    float4 c = *(const float4*)(src + 4);
    u16x8 r;
    r[0] = f2bf(a.x); r[1] = f2bf(a.y); r[2] = f2bf(a.z); r[3] = f2bf(a.w);
    r[4] = f2bf(c.x); r[5] = f2bf(c.y); r[6] = f2bf(c.z); r[7] = f2bf(c.w);
    *(u16x8*)dst = r;
}

// ---------------- f32 -> bf16 conversion (linear) -------------------------
__global__ __launch_bounds__(256) void k_cvt(const float* __restrict__ in,
                                             unsigned short* __restrict__ out,
                                             long n8) {
    long i = (long)blockIdx.x * blockDim.x + threadIdx.x;
    long stride = (long)gridDim.x * blockDim.x;
    for (; i < n8; i += stride) cvt8(in + i * 8, out + i * 8);
}

// ---------------- f32 -> bf16 with w1/w3 16-row interleave ----------------
// w13b[e] row layout: rr = (h>>4)*32 + which*16 + (h&15); which 0=w1, 1=w3.
__global__ __launch_bounds__(256) void k_cvt_w13(
    const float* __restrict__ in, unsigned short* __restrict__ out,
    int which) {
    const long n8 = (long)E * H * D / 8;
    long i = (long)blockIdx.x * blockDim.x + threadIdx.x;
    long stride = (long)gridDim.x * blockDim.x;
    for (; i < n8; i += stride) {
        int col8 = (int)(i & 255);          // D/8 = 256
        int row = (int)(i >> 8);            // e*H + h
        int e = row / H;
        int h = row - e * H;
        int rr = ((h >> 4) << 5) + (which << 4) + (h & 15);
        cvt8(in + i * 8,
             out + ((size_t)e * (2 * H) + rr) * D + (size_t)col8 * 8);
    }
}

// ---------------- expert lookup for a row tile ----------------------------
DEV int expert_of_row(const int* __restrict__ ntp, int row0) {
    int e = 0, s = 0;
    for (int i = 0; i < E; ++i) {
        int c = ntp[i];
        if (row0 < s + c) { e = i; break; }
        s += c;
    }
    return e;
}

// ---------------- 256x256 BK=32 ring-4 GEMM core --------------------------
// 512 thr = 8 waves (2M x 4N); wave out 128x64 = acc[8][4] f32x4.
// LDS: sA,sB = 4 slots x 256 rows x 32 el (64B rows) = 32 KiB per slot pair.
// Swizzle: 16B slot s' of row r holds k-quarter q = s' ^ ((r>>1)&3).
// Staging: per-wave 4 gloads/tile (2 A + 2 B), linear LDS dest, source
// k-slot = (l&3)^((l>>3)&3) (per-lane constant). Stage tile t+3 during
// tile t; ONE vmcnt(8) + ONE s_barrier per tile.
template <int LD, int NT>
DEV void gemm_ring4(const unsigned short* pa, const unsigned short* pb,
                    unsigned short* sA, unsigned short* sB, int tid,
                    f32x4 (&acc)[8][4]) {
    const int lane = tid & 63, wid = tid >> 6;
    const int wm = wid >> 2, wn = wid & 3;

    // LDS read bases (ushort units): frag mi at a0 + mi*512, ni at b0 + ni*512
    const int q = lane >> 4;
    const int ar = wm * 128 + (lane & 15);
    const int a0 = ar * 32 + ((q ^ ((ar >> 1) & 3)) << 3);
    const int br = wn * 64 + (lane & 15);
    const int b0 = br * 32 + ((q ^ ((br >> 1) & 3)) << 3);

    // staging dest (wave-uniform byte base; HW adds lane*16)
    char* ldsA = (char*)sA;
    char* ldsB = (char*)sB;
    const int dW = wid << 10;  // wid*1024

    auto stage = [&](int t) {
        const int so = (t & 3) << 14;  // slot*16384 bytes
        const unsigned short* ga = pa + t * 32;
        const unsigned short* gb = pb + t * 32;
        gload16(ga, ldsA + so + dW);
        gload16(ga + (size_t)128 * LD, ldsA + so + dW + 8192);
        gload16(gb, ldsB + so + dW);
        gload16(gb + (size_t)128 * LD, ldsB + so + dW + 8192);
    };

    // prologue: 3 tiles in flight
    stage(0); stage(1); stage(2);

#pragma unroll 1
    for (int t = 0; t < NT; ++t) {
        if (t < NT - 2)       asm volatile("s_waitcnt vmcnt(8)" ::: "memory");
        else if (t == NT - 2) asm volatile("s_waitcnt vmcnt(4)" ::: "memory");
        else                  asm volatile("s_waitcnt vmcnt(0)" ::: "memory");
        __builtin_amdgcn_s_barrier();
        __builtin_amdgcn_sched_barrier(0);
        if (t + 3 < NT) stage(t + 3);

        const unsigned short* A = sA + ((t & 3) << 13) + a0;  // slot*8192
        const unsigned short* B = sB + ((t & 3) << 13) + b0;
        bf16x8 a[8], b[4];
#pragma unroll
        for (int mi = 0; mi < 8; ++mi)
            a[mi] = *(const bf16x8*)(A + mi * 512);
#pragma unroll
        for (int ni = 0; ni < 4; ++ni)
            b[ni] = *(const bf16x8*)(B + ni * 512);

        __builtin_amdgcn_s_setprio(1);
#pragma unroll
        for (int mi = 0; mi < 8; ++mi)
#pragma unroll
            for (int ni = 0; ni < 4; ++ni)
                acc[mi][ni] = mfma16(a[mi], b[ni], acc[mi][ni]);
        __builtin_amdgcn_s_setprio(0);
    }
}

// ---------------- kernel 1: fused gate/up grouped GEMM + SwiGLU -----------
// A = xb (T x D), B = w13b[e] (2H x D interleave-16), h (T x H bf16).
__global__ __launch_bounds__(512, 2) void k_gate_up(
    const unsigned short* __restrict__ xb,
    const unsigned short* __restrict__ w13b,
    const int* __restrict__ ntp,
    unsigned short* __restrict__ hbuf) {
    __shared__ unsigned short sA[4 * 8192];
    __shared__ unsigned short sB[4 * 8192];

    const int nwg = gridDim.x;           // 2816
    const int cpx = nwg >> 3;
    const int bid = blockIdx.x;
    const int swz = (bid & 7) * cpx + (bid >> 3);
    const int tm = swz & 63;             // tm fastest: B-panel L2 reuse
    const int tn = swz >> 6;             // 0..43

    const int row0 = tm << 8;
    const int e = expert_of_row(ntp, row0);
    const int tid = threadIdx.x;
    const int lane = tid & 63, wid = tid >> 6;

    // staging sources: row = wid*16 + (lane>>2), k-slot (l&3)^((l>>3)&3)
    const int srow = wid * 16 + (lane >> 2);
    const int sq = (lane & 3) ^ ((lane >> 3) & 3);
    const unsigned short* pa = xb + (size_t)(row0 + srow) * D + sq * 8;
    const unsigned short* pb = w13b + (size_t)e * (2 * H) * D +
                               (size_t)((tn << 8) + srow) * D + sq * 8;

    f32x4 acc[8][4] = {};
    gemm_ring4<D, D / 32>(pa, pb, sA, sB, tid, acc);

    // Epilogue: ni pairs (0,1),(2,3) = (gate,up). C/D: col=lane&15,
    // row=(lane>>4)*4+j.
    const int wm = wid >> 2, wn = wid & 3;
    const int rbase = row0 + (wm << 7) + ((lane >> 4) << 2);
    const int cb = (((tn << 3) + (wn << 1)) << 4) + (lane & 15);
#pragma unroll
    for (int mi = 0; mi < 8; ++mi)
#pragma unroll
        for (int pi = 0; pi < 2; ++pi) {
            f32x4 g = acc[mi][2 * pi], u = acc[mi][2 * pi + 1];
            const int hcol = cb + (pi << 4);
#pragma unroll
            for (int j = 0; j < 4; ++j) {
                float gv = g[j];
                float hv = gv * u[j] / (1.f + __expf(-gv));
                hbuf[(size_t)(rbase + (mi << 4) + j) * H + hcol] = f2bf(hv);
            }
        }
}

// ---------------- kernel 2: down grouped GEMM -----------------------------
// A = h (T x H), B = w2b[e] (D x H), out (T x D f32). K = H = 5632.
__global__ __launch_bounds__(512, 2) void k_down(
    const unsigned short* __restrict__ hbuf,
    const unsigned short* __restrict__ w2b,
    const int* __restrict__ ntp,
    float* __restrict__ out) {
    __shared__ unsigned short sA[4 * 8192];
    __shared__ unsigned short sB[4 * 8192];

    const int nwg = gridDim.x;           // 512
    const int cpx = nwg >> 3;
    const int bid = blockIdx.x;
    const int swz = (bid & 7) * cpx + (bid >> 3);
    const int tm = swz & 63;
    const int tn = swz >> 6;             // 0..7

    const int row0 = tm << 8;
    const int e = expert_of_row(ntp, row0);
    const int tid = threadIdx.x;
    const int lane = tid & 63, wid = tid >> 6;

    const int srow = wid * 16 + (lane >> 2);
    const int sq = (lane & 3) ^ ((lane >> 3) & 3);
    const unsigned short* pa = hbuf + (size_t)(row0 + srow) * H + sq * 8;
    const unsigned short* pb = w2b + (size_t)e * D * H +
                               (size_t)((tn << 8) + srow) * H + sq * 8;

    f32x4 acc[8][4] = {};
    gemm_ring4<H, H / 32>(pa, pb, sA, sB, tid, acc);

    const int wm = wid >> 2, wn = wid & 3;
    const int rbase = row0 + (wm << 7) + ((lane >> 4) << 2);
    const int cb = (tn << 8) + (wn << 6) + (lane & 15);
#pragma unroll
    for (int mi = 0; mi < 8; ++mi)
#pragma unroll
        for (int ni = 0; ni < 4; ++ni) {
            f32x4 c = acc[mi][ni];
#pragma unroll
            for (int j = 0; j < 4; ++j)
                out[(size_t)(rbase + (mi << 4) + j) * D + cb + (ni << 4)] =
                    c[j];
        }
}

extern "C" void kernel_launch(void* const* d_in, const int* in_sizes, int n_in,
                              void* d_out, int out_size, void* d_ws,
                              size_t ws_size, hipStream_t stream) {
    const float* x = (const float*)d_in[0];
    const float* w1 = (const float*)d_in[1];
    const float* w2 = (const float*)d_in[2];
    const float* w3 = (const float*)d_in[3];
    const int* ntp = (const int*)d_in[4];
    float* out = (float*)d_out;

    char* ws = (char*)d_ws;
    // ws layout (bytes):
    //   xb  : [0, 64MiB)                 T*D*2
    //   w13b: [64MiB, 64+352MiB)         E*2H*D*2  (reused for w2b)
    //   h   : [416MiB, 448MiB)           T*H*2
    unsigned short* xb = (unsigned short*)(ws + 0);
    unsigned short* w13b = (unsigned short*)(ws + 67108864L);
    unsigned short* hbuf = (unsigned short*)(ws + 67108864L + 385875968L);
    unsigned short* w2b = w13b;  // dead after k_gate_up

    k_cvt<<<2048, 256, 0, stream>>>(x, xb, (long)T * D / 8);
    k_cvt_w13<<<2048, 256, 0, stream>>>(w1, w13b, 0);
    k_cvt_w13<<<2048, 256, 0, stream>>>(w3, w13b, 1);

    k_gate_up<<<(T / 256) * (2 * H / 256), 512, 0, stream>>>(xb, w13b, ntp,
                                                             hbuf);

    k_cvt<<<2048, 256, 0, stream>>>(w2, w2b, (long)E * D * H / 8);

    k_down<<<(T / 256) * (D / 256), 512, 0, stream>>>(hbuf, w2b, ntp, out);
}

// Round 6
// 1464.695 us; speedup vs baseline: 1.2487x; 1.2487x over previous
//
#include <hip/hip_runtime.h>
#include <hip/hip_bf16.h>

// GroupedExperts: out[t] = (silu(x@w1[e]^T) * (x@w3[e]^T)) @ w2[e]^T
// E=8, T=16384, D=2048, H=5632; tokens pre-sorted by expert, even split.
//
// Round 6: m201-faithful 4-phase schedule. 256x256 tile, BK=64, 8 waves
// (2Mx4N), 2-buf LDS split into K-slices (A-kk0/B-kk0/A-kk1/B-kk1, each
// 256x32 = 16KB = 2 gloads/thread), one half-tile staged per phase.
// Phase = {ds_read 8|4 ; stage ; [vmcnt(4) on odd phases] ; barrier ;
// lgkmcnt(0) ; setprio(1) 16xMFMA setprio(0) ; barrier}. vmcnt never 0
// in steady state; stage->wait distance = 4 phases. Swizzle q^=(row>>1)&3
// on 64B rows (measured conflict-free in R5), inverse-swizzled global
// source, linear global_load_lds dest.

typedef __bf16 bf16x8 __attribute__((ext_vector_type(8)));
typedef float f32x4 __attribute__((ext_vector_type(4)));
typedef unsigned short u16x8 __attribute__((ext_vector_type(8)));

constexpr int E = 8;
constexpr int T = 16384;
constexpr int D = 2048;
constexpr int H = 5632;

#define DEV static __device__ __forceinline__

DEV unsigned short f2bf(float f) {
    unsigned u = __builtin_bit_cast(unsigned, f);
    u = (u + 0x7FFFu + ((u >> 16) & 1u)) >> 16;   // RNE
    return (unsigned short)u;
}

DEV void gload16(const void* g, void* l) {
    __builtin_amdgcn_global_load_lds(
        (const __attribute__((address_space(1))) void*)g,
        (__attribute__((address_space(3))) void*)l, 16, 0, 0);
}

DEV f32x4 mfma16(bf16x8 a, bf16x8 b, f32x4 c) {
    return __builtin_amdgcn_mfma_f32_16x16x32_bf16(a, b, c, 0, 0, 0);
}

DEV void cvt8(const float* src, unsigned short* dst) {
    float4 a = *(const float4*)src;
    float4 c = *(const float4*)(src + 4);
    u16x8 r;
    r[0] = f2bf(a.x); r[1] = f2bf(a.y); r[2] = f2bf(a.z); r[3] = f2bf(a.w);
    r[4] = f2bf(c.x); r[5] = f2bf(c.y); r[6] = f2bf(c.z); r[7] = f2bf(c.w);
    *(u16x8*)dst = r;
}

// ---------------- f32 -> bf16 conversion (linear) -------------------------
__global__ __launch_bounds__(256) void k_cvt(const float* __restrict__ in,
                                             unsigned short* __restrict__ out,
                                             long n8) {
    long i = (long)blockIdx.x * blockDim.x + threadIdx.x;
    long stride = (long)gridDim.x * blockDim.x;
    for (; i < n8; i += stride) cvt8(in + i * 8, out + i * 8);
}

// ---------------- f32 -> bf16 with w1/w3 16-row interleave ----------------
// w13b[e] row layout: rr = (h>>4)*32 + which*16 + (h&15); which 0=w1, 1=w3.
__global__ __launch_bounds__(256) void k_cvt_w13(
    const float* __restrict__ in, unsigned short* __restrict__ out,
    int which) {
    const long n8 = (long)E * H * D / 8;
    long i = (long)blockIdx.x * blockDim.x + threadIdx.x;
    long stride = (long)gridDim.x * blockDim.x;
    for (; i < n8; i += stride) {
        int col8 = (int)(i & 255);          // D/8 = 256
        int row = (int)(i >> 8);            // e*H + h
        int e = row / H;
        int h = row - e * H;
        int rr = ((h >> 4) << 5) + (which << 4) + (h & 15);
        cvt8(in + i * 8,
             out + ((size_t)e * (2 * H) + rr) * D + (size_t)col8 * 8);
    }
}

// ---------------- expert lookup for a row tile ----------------------------
DEV int expert_of_row(const int* __restrict__ ntp, int row0) {
    int e = 0, s = 0;
    for (int i = 0; i < E; ++i) {
        int c = ntp[i];
        if (row0 < s + c) { e = i; break; }
        s += c;
    }
    return e;
}

// ---------------- 256x256 BK=64 4-phase GEMM core -------------------------
// 512 thr = 8 waves (2M x 4N); wave out 128x64 = acc[8][4] f32x4.
// LDS per operand: 2 buf x 2 kk-slice x (256 rows x 32 el, 64B rows) = 64KB.
// Swizzle: 16B quarter q of row r stored at q ^ ((r>>1)&3).
// Phases (16 MFMA each): p0 rd{A m0-3 kk0, B kk0} st A-kk0(t+1)
//                        p1 rd{A m4-7 kk0}        st B-kk0(t+1) vm4
//                        p2 rd{A m0-3 kk1, B kk1} st A-kk1(t+1)
//                        p3 rd{A m4-7 kk1}        st B-kk1(t+1) vm4
// Ledger: prologue stages 4 halves (8 loads), vm4 retires kk0 pair; each
// odd-phase vm4 retires the pair needed 1 phase later; tail uses vm0 once.
template <int LD, int NT>
DEV void gemm_4p(const unsigned short* pa, const unsigned short* pb,
                 unsigned short* sA, unsigned short* sB, int tid,
                 f32x4 (&acc)[8][4]) {
    const int lane = tid & 63, wid = tid >> 6;
    const int wm = wid >> 2, wn = wid & 3;

    // LDS read bases (ushort units); frag m at +m*512, kk1 slice at +8192
    const int q8 = (((lane >> 4) ^ ((lane >> 1) & 3)) << 3);
    const int aoff = (wm * 128 + (lane & 15)) * 32 + q8;
    const int boff = (wn * 64 + (lane & 15)) * 32 + q8;

    // staging dest: wave-uniform base (HW adds lane*16)
    char* lA = (char*)sA;
    char* lB = (char*)sB;
    const int dW = wid << 10;

    auto stA = [&](int t, int kk) {
        const unsigned short* g = pa + (size_t)t * 64 + kk * 32;
        char* l = lA + ((t & 1) << 15) + (kk << 14) + dW;
        gload16(g, l);
        gload16(g + (size_t)128 * LD, l + 8192);
    };
    auto stB = [&](int t, int kk) {
        const unsigned short* g = pb + (size_t)t * 64 + kk * 32;
        char* l = lB + ((t & 1) << 15) + (kk << 14) + dW;
        gload16(g, l);
        gload16(g + (size_t)128 * LD, l + 8192);
    };

    // prologue: tile 0 (all 4 half-tiles) -> buf0
    stA(0, 0); stB(0, 0); stA(0, 1); stB(0, 1);
    asm volatile("s_waitcnt vmcnt(4)" ::: "memory");  // retire kk0 pair
    __builtin_amdgcn_s_barrier();

#pragma unroll 1
    for (int t = 0; t < NT; ++t) {
        const int sb = (t & 1) << 14;                 // buf base, ushorts
        const unsigned short* A0 = sA + sb + aoff;    // kk0
        const unsigned short* B0 = sB + sb + boff;
        const unsigned short* A1 = A0 + 8192;         // kk1
        const unsigned short* B1 = B0 + 8192;
        const bool more = (t + 1 < NT);
        bf16x8 a[4], b[4];

        // ===== p0 =====
#pragma unroll
        for (int i = 0; i < 4; ++i) a[i] = *(const bf16x8*)(A0 + i * 512);
#pragma unroll
        for (int i = 0; i < 4; ++i) b[i] = *(const bf16x8*)(B0 + i * 512);
        if (more) stA(t + 1, 0);
        __builtin_amdgcn_s_barrier();
        asm volatile("s_waitcnt lgkmcnt(0)" ::: "memory");
        __builtin_amdgcn_sched_barrier(0);
        __builtin_amdgcn_s_setprio(1);
#pragma unroll
        for (int m = 0; m < 4; ++m)
#pragma unroll
            for (int n = 0; n < 4; ++n)
                acc[m][n] = mfma16(a[m], b[n], acc[m][n]);
        __builtin_amdgcn_s_setprio(0);
        __builtin_amdgcn_s_barrier();

        // ===== p1 =====
#pragma unroll
        for (int i = 0; i < 4; ++i)
            a[i] = *(const bf16x8*)(A0 + 2048 + i * 512);
        if (more) {
            stB(t + 1, 0);
            asm volatile("s_waitcnt vmcnt(4)" ::: "memory");
        } else {
            asm volatile("s_waitcnt vmcnt(0)" ::: "memory");
        }
        __builtin_amdgcn_s_barrier();
        asm volatile("s_waitcnt lgkmcnt(0)" ::: "memory");
        __builtin_amdgcn_sched_barrier(0);
        __builtin_amdgcn_s_setprio(1);
#pragma unroll
        for (int m = 0; m < 4; ++m)
#pragma unroll
            for (int n = 0; n < 4; ++n)
                acc[4 + m][n] = mfma16(a[m], b[n], acc[4 + m][n]);
        __builtin_amdgcn_s_setprio(0);
        __builtin_amdgcn_s_barrier();

        // ===== p2 =====
#pragma unroll
        for (int i = 0; i < 4; ++i) a[i] = *(const bf16x8*)(A1 + i * 512);
#pragma unroll
        for (int i = 0; i < 4; ++i) b[i] = *(const bf16x8*)(B1 + i * 512);
        if (more) stA(t + 1, 1);
        __builtin_amdgcn_s_barrier();
        asm volatile("s_waitcnt lgkmcnt(0)" ::: "memory");
        __builtin_amdgcn_sched_barrier(0);
        __builtin_amdgcn_s_setprio(1);
#pragma unroll
        for (int m = 0; m < 4; ++m)
#pragma unroll
            for (int n = 0; n < 4; ++n)
                acc[m][n] = mfma16(a[m], b[n], acc[m][n]);
        __builtin_amdgcn_s_setprio(0);
        __builtin_amdgcn_s_barrier();

        // ===== p3 =====
#pragma unroll
        for (int i = 0; i < 4; ++i)
            a[i] = *(const bf16x8*)(A1 + 2048 + i * 512);
        if (more) {
            stB(t + 1, 1);
            asm volatile("s_waitcnt vmcnt(4)" ::: "memory");
        }
        __builtin_amdgcn_s_barrier();
        asm volatile("s_waitcnt lgkmcnt(0)" ::: "memory");
        __builtin_amdgcn_sched_barrier(0);
        __builtin_amdgcn_s_setprio(1);
#pragma unroll
        for (int m = 0; m < 4; ++m)
#pragma unroll
            for (int n = 0; n < 4; ++n)
                acc[4 + m][n] = mfma16(a[m], b[n], acc[4 + m][n]);
        __builtin_amdgcn_s_setprio(0);
        __builtin_amdgcn_s_barrier();
    }
}

// ---------------- kernel 1: fused gate/up grouped GEMM + SwiGLU -----------
// A = xb (T x D), B = w13b[e] (2H x D interleave-16), h (T x H bf16).
__global__ __launch_bounds__(512, 2) void k_gate_up(
    const unsigned short* __restrict__ xb,
    const unsigned short* __restrict__ w13b,
    const int* __restrict__ ntp,
    unsigned short* __restrict__ hbuf) {
    __shared__ unsigned short sA[2 * 2 * 8192];
    __shared__ unsigned short sB[2 * 2 * 8192];

    const int nwg = gridDim.x;           // 2816
    const int cpx = nwg >> 3;
    const int bid = blockIdx.x;
    const int swz = (bid & 7) * cpx + (bid >> 3);
    const int tm = swz & 63;             // tm fastest: B-panel L2 reuse
    const int tn = swz >> 6;             // 0..43

    const int row0 = tm << 8;
    const int e = expert_of_row(ntp, row0);
    const int tid = threadIdx.x;
    const int lane = tid & 63, wid = tid >> 6;

    // staging sources: row = tid>>2 (+j*128), k-quarter (tid&3)^((tid>>3)&3)
    const int srow = tid >> 2;
    const int sq = (tid & 3) ^ ((tid >> 3) & 3);
    const unsigned short* pa = xb + (size_t)(row0 + srow) * D + sq * 8;
    const unsigned short* pb = w13b + (size_t)e * (2 * H) * D +
                               (size_t)((tn << 8) + srow) * D + sq * 8;

    f32x4 acc[8][4] = {};
    gemm_4p<D, D / 64>(pa, pb, sA, sB, tid, acc);

    // Epilogue: ni pairs (0,1),(2,3) = (gate,up). C/D: col=lane&15,
    // row=(lane>>4)*4+j.
    const int wm = wid >> 2, wn = wid & 3;
    const int rbase = row0 + (wm << 7) + ((lane >> 4) << 2);
    const int cb = (((tn << 3) + (wn << 1)) << 4) + (lane & 15);
#pragma unroll
    for (int mi = 0; mi < 8; ++mi)
#pragma unroll
        for (int pi = 0; pi < 2; ++pi) {
            f32x4 g = acc[mi][2 * pi], u = acc[mi][2 * pi + 1];
            const int hcol = cb + (pi << 4);
#pragma unroll
            for (int j = 0; j < 4; ++j) {
                float gv = g[j];
                float hv = gv * u[j] / (1.f + __expf(-gv));
                hbuf[(size_t)(rbase + (mi << 4) + j) * H + hcol] = f2bf(hv);
            }
        }
}

// ---------------- kernel 2: down grouped GEMM -----------------------------
// A = h (T x H), B = w2b[e] (D x H), out (T x D f32). K = H = 5632.
__global__ __launch_bounds__(512, 2) void k_down(
    const unsigned short* __restrict__ hbuf,
    const unsigned short* __restrict__ w2b,
    const int* __restrict__ ntp,
    float* __restrict__ out) {
    __shared__ unsigned short sA[2 * 2 * 8192];
    __shared__ unsigned short sB[2 * 2 * 8192];

    const int nwg = gridDim.x;           // 512
    const int cpx = nwg >> 3;
    const int bid = blockIdx.x;
    const int swz = (bid & 7) * cpx + (bid >> 3);
    const int tm = swz & 63;
    const int tn = swz >> 6;             // 0..7

    const int row0 = tm << 8;
    const int e = expert_of_row(ntp, row0);
    const int tid = threadIdx.x;
    const int lane = tid & 63, wid = tid >> 6;

    const int srow = tid >> 2;
    const int sq = (tid & 3) ^ ((tid >> 3) & 3);
    const unsigned short* pa = hbuf + (size_t)(row0 + srow) * H + sq * 8;
    const unsigned short* pb = w2b + (size_t)e * D * H +
                               (size_t)((tn << 8) + srow) * H + sq * 8;

    f32x4 acc[8][4] = {};
    gemm_4p<H, H / 64>(pa, pb, sA, sB, tid, acc);

    const int wm = wid >> 2, wn = wid & 3;
    const int rbase = row0 + (wm << 7) + ((lane >> 4) << 2);
    const int cb = (tn << 8) + (wn << 6) + (lane & 15);
#pragma unroll
    for (int mi = 0; mi < 8; ++mi)
#pragma unroll
        for (int ni = 0; ni < 4; ++ni) {
            f32x4 c = acc[mi][ni];
#pragma unroll
            for (int j = 0; j < 4; ++j)
                out[(size_t)(rbase + (mi << 4) + j) * D + cb + (ni << 4)] =
                    c[j];
        }
}

extern "C" void kernel_launch(void* const* d_in, const int* in_sizes, int n_in,
                              void* d_out, int out_size, void* d_ws,
                              size_t ws_size, hipStream_t stream) {
    const float* x = (const float*)d_in[0];
    const float* w1 = (const float*)d_in[1];
    const float* w2 = (const float*)d_in[2];
    const float* w3 = (const float*)d_in[3];
    const int* ntp = (const int*)d_in[4];
    float* out = (float*)d_out;

    char* ws = (char*)d_ws;
    // ws layout (bytes):
    //   xb  : [0, 64MiB)                 T*D*2
    //   w13b: [64MiB, 64+352MiB)         E*2H*D*2  (reused for w2b)
    //   h   : [416MiB, 448MiB)           T*H*2
    unsigned short* xb = (unsigned short*)(ws + 0);
    unsigned short* w13b = (unsigned short*)(ws + 67108864L);
    unsigned short* hbuf = (unsigned short*)(ws + 67108864L + 385875968L);
    unsigned short* w2b = w13b;  // dead after k_gate_up

    k_cvt<<<2048, 256, 0, stream>>>(x, xb, (long)T * D / 8);
    k_cvt_w13<<<2048, 256, 0, stream>>>(w1, w13b, 0);
    k_cvt_w13<<<2048, 256, 0, stream>>>(w3, w13b, 1);

    k_gate_up<<<(T / 256) * (2 * H / 256), 512, 0, stream>>>(xb, w13b, ntp,
                                                             hbuf);

    k_cvt<<<2048, 256, 0, stream>>>(w2, w2b, (long)E * D * H / 8);

    k_down<<<(T / 256) * (D / 256), 512, 0, stream>>>(hbuf, w2b, ntp, out);
}